// Round 19
// baseline (330.684 us; speedup 1.0000x reference)
//
#include <hip/hip_runtime.h>
#include <hip/hip_bf16.h>
#include <cstdint>

#define DI __device__ __forceinline__

using bf16x8 = __attribute__((ext_vector_type(8))) short;
using f32x4  = __attribute__((ext_vector_type(4))) float;
using f32x16 = __attribute__((ext_vector_type(16))) float;

constexpr int IN_DIM = 384;
constexpr int HID    = 512;
constexpr int KTOT   = IN_DIM * 20;          // 7680: k = i*20 + t
constexpr int BM = 128, BN = 256, BK = 160;  // 8 input dims per K-step
constexpr int NSTEP = KTOT / BK;             // 48
// A: double-buffered LDS, stride 320 + bijective XOR (addr^(row&7)<<4) on write & read.
//    ONE barrier per step. (R18-verbatim)
// B: fragment-linear global (L2-resident), now packed for 32x32x16 MFMA: fragment
//    (g=o>>5, q=k>>4) is 1KB contiguous; lane=(o&31)+(((k&15)>>3)<<5), elem j=k&7.
// MFMA switched 16x16x32 -> 32x32x16: 8 instr per K-32 per wave (was 16) -- halves
//    MFMA issue pressure (R18 showed MfmaUtil 36 + VALUBusy 35 = issue contention).
constexpr int A_STRIDE_B = 320;
constexpr int A_BYTES    = BM * A_STRIDE_B;        // 40960
constexpr int LDS_BYTES  = 2 * A_BYTES;            // 81920 -> 2 blocks/CU

DI unsigned short f2bf(float f) {
  union { float f; uint32_t u; } v; v.f = f;
  uint32_t r = (v.u + 0x7FFFu + ((v.u >> 16) & 1u)) >> 16;
  return (unsigned short)r;
}
DI float fast_tanh(float x) {
  float e = __expf(2.0f * x);
  return 1.0f - 2.0f / (e + 1.0f);
}
DI uint32_t swzw(uint32_t L) { return L ^ ((L >> 6) & 0x70u); }

// ---------------- kpack: W -> bf16 fragment-linear Wf (32x32x16 layout) ----------------
// Element (o,k): g = o>>5 (16 frags), q = k>>4 (480 planes); lane = (o&31) + ((k>>3)&1)*32;
// elem offset = (q*16 + g)*512 + lane*8 + (k&7).  k = i*20 + c; c==0 -> base else spline.
__global__ __launch_bounds__(256) void kpack(const float* __restrict__ bw,
                                             const float* __restrict__ sw,
                                             unsigned short* __restrict__ Wf) {
  int idx = blockIdx.x * 256 + threadIdx.x;   // o*384 + i
  int o = idx / IN_DIM;
  int i = idx - o * IN_DIM;
  const float* sp = sw + (size_t)idx * 19;
  const uint32_t g   = (uint32_t)(o >> 5);
  const uint32_t l32 = (uint32_t)(o & 31);
#pragma unroll
  for (int c = 0; c < 20; ++c) {
    int k = i * 20 + c;
    uint32_t q  = (uint32_t)k >> 4;
    uint32_t kr = (uint32_t)k & 15u;
    uint32_t lane = l32 + ((kr >> 3) << 5);
    uint32_t off = (q * 16u + g) * 512u + lane * 8u + (kr & 7u);
    float v = (c == 0) ? bw[idx] : sp[c - 1];
    Wf[off] = f2bf(v);
  }
}

// ---------------- fused KAN GEMM: h = tanh(A(x) @ W^T), 8 waves, wave tile 64x64 ----------------
__global__ __launch_bounds__(512, 2) void kgemm1(const float* __restrict__ z,
                                                 const float* __restrict__ ms,
                                                 const float* __restrict__ md,
                                                 const unsigned short* __restrict__ Wf,
                                                 unsigned short* __restrict__ hout) {
  extern __shared__ char ldsbuf[];            // [A0 @0][A1 @40960]

  const int tid  = threadIdx.x;
  const int lane = tid & 63;
  const int wv   = tid >> 6;                  // 0..7
  const int wr   = wv >> 2;                   // 0..1 : M strip (64 rows)
  const int wc   = wv & 3;                    // 0..3 : N strip (64 cols)
  const int l32  = lane & 31;
  const int lhi2 = lane >> 5;                 // 0..1

  // XCD-aware bijective swizzle: grid 512 = 8 XCD * 64; XCDs 0-3 -> nblk 0, 4-7 -> nblk 1
  int wg = blockIdx.x;
  int id = (wg & 7) * 64 + (wg >> 3);
  const int mblk = id & 255;
  const int nblk = id >> 8;
  const int row0 = mblk * BM;
  const int col0 = nblk * BN;

  // B global fragment base: g = nblk*8 + wc*2 + n (n in {0,1}); q = s*10 + ks*2 + kk
  const unsigned short* bpt = Wf + (size_t)(nblk * 8 + wc * 2) * 512 + (size_t)lane * 8;

  // A-gen: isl constant per thread; 2 rows (arow0, arow0+64) per thread
  const int isl = tid & 7;
  const int arow0 = tid >> 3;                 // 0..63
  const uint32_t fw = ((uint32_t)arow0 & 7u) << 4;   // (row&7) invariant under +64

  // A fragment read base: row = wr*64 + m*32 + (lane&31); row&7 = lane&7
  const uint32_t fA = (uint32_t)(lane & 7) << 4;
  const uint32_t rA = (uint32_t)(wr * 64 + l32) * A_STRIDE_B + (uint32_t)lhi2 * 16u;

  f32x16 acc[2][2] = {};

  // ---- prologue: stage A(0) into parity 0; prefetch x(1)
  float xv0, xv1;
  {
    const float* xcol = z + isl;              // s=0 -> i=isl<128 -> z
    float x0 = xcol[(size_t)(row0 + arow0) * 128];
    float x1 = xcol[(size_t)(row0 + arow0 + 64) * 128];
#pragma unroll
    for (int r = 0; r < 2; ++r) {
      float x = (r == 0) ? x0 : x1;
      int arow = arow0 + r * 64;
      float xt = fast_tanh(x);
      float tt = (xt + 1.0f) * 8.0f;
      int   m  = (int)tt; m = m > 16 ? 16 : m;
      float u  = tt - (float)m;
      float omu = 1.0f - u;
      float u2 = u * u, u3 = u2 * u;
      float w0 = omu * omu * omu * (1.0f / 6.0f);
      float w1 = (3.0f * u3 - 6.0f * u2 + 4.0f) * (1.0f / 6.0f);
      float w2 = (-3.0f * u3 + 3.0f * u2 + 3.0f * u + 1.0f) * (1.0f / 6.0f);
      float w3 = u3 * (1.0f / 6.0f);
      float sil = xt / (1.0f + __expf(-xt));
      uint32_t base = (uint32_t)arow * A_STRIDE_B + (uint32_t)isl * 40u;
#pragma unroll
      for (int zz = 0; zz < 5; ++zz)
        *(uint64_t*)(ldsbuf + ((base + zz * 8) ^ fw)) = 0ull;
      *(short*)(ldsbuf + (base ^ fw)) = (short)f2bf(sil);
      *(short*)(ldsbuf + ((base + 2u * (m + 1)) ^ fw)) = (short)f2bf(w0);
      *(short*)(ldsbuf + ((base + 2u * (m + 2)) ^ fw)) = (short)f2bf(w1);
      *(short*)(ldsbuf + ((base + 2u * (m + 3)) ^ fw)) = (short)f2bf(w2);
      if (m < 16)
        *(short*)(ldsbuf + ((base + 2u * (m + 4)) ^ fw)) = (short)f2bf(w3);
    }
    const float* xc1 = z + (8 + isl);         // i = 8+isl < 128 -> z
    xv0 = xc1[(size_t)(row0 + arow0) * 128];
    xv1 = xc1[(size_t)(row0 + arow0 + 64) * 128];
  }
  __syncthreads();

  for (int s = 0; s < NSTEP; ++s) {
    const uint32_t pc = (uint32_t)(s & 1);
    const uint32_t pn = pc ^ 1u;
    char* An = ldsbuf + pn * (uint32_t)A_BYTES;
    const char* Ac = ldsbuf + pc * (uint32_t)A_BYTES;

    float xn0 = 0.f, xn1 = 0.f;
    if (s + 1 < NSTEP) {
      // ---- stage A(s+1) into An using xv = x(s+1)
#pragma unroll
      for (int r = 0; r < 2; ++r) {
        float x = (r == 0) ? xv0 : xv1;
        int arow = arow0 + r * 64;
        float xt = fast_tanh(x);
        float tt = (xt + 1.0f) * 8.0f;
        int   m  = (int)tt; m = m > 16 ? 16 : m;
        float u  = tt - (float)m;
        float omu = 1.0f - u;
        float u2 = u * u, u3 = u2 * u;
        float w0 = omu * omu * omu * (1.0f / 6.0f);
        float w1 = (3.0f * u3 - 6.0f * u2 + 4.0f) * (1.0f / 6.0f);
        float w2 = (-3.0f * u3 + 3.0f * u2 + 3.0f * u + 1.0f) * (1.0f / 6.0f);
        float w3 = u3 * (1.0f / 6.0f);
        float sil = xt / (1.0f + __expf(-xt));
        uint32_t base = (uint32_t)arow * A_STRIDE_B + (uint32_t)isl * 40u;
#pragma unroll
        for (int zz = 0; zz < 5; ++zz)
          *(uint64_t*)(An + ((base + zz * 8) ^ fw)) = 0ull;
        *(short*)(An + (base ^ fw)) = (short)f2bf(sil);
        *(short*)(An + ((base + 2u * (m + 1)) ^ fw)) = (short)f2bf(w0);
        *(short*)(An + ((base + 2u * (m + 2)) ^ fw)) = (short)f2bf(w1);
        *(short*)(An + ((base + 2u * (m + 3)) ^ fw)) = (short)f2bf(w2);
        if (m < 16)
          *(short*)(An + ((base + 2u * (m + 4)) ^ fw)) = (short)f2bf(w3);
      }
      // ---- prefetch x(s+2)
      if (s + 2 < NSTEP) {
        int i = (s + 2) * 8 + isl;
        const float* src = (i < 128) ? z : (i < 256 ? ms : md);
        const float* xcol = src + (i & 127);
        xn0 = xcol[(size_t)(row0 + arow0) * 128];
        xn1 = xcol[(size_t)(row0 + arow0 + 64) * 128];
      }
    }

    // ---- compute(s): 5 K-sub-steps of 32; 2x2 of 32x32x16 MFMA, 2 kk each
    const unsigned short* bq = bpt + (size_t)(s * 10) * 8192u;   // q = s*10 + ks*2 + kk
#pragma unroll
    for (int ks = 0; ks < 5; ++ks) {
      bf16x8 af[2][2], bfr[2][2];             // [m][kk], [kk][n]
#pragma unroll
      for (int kk = 0; kk < 2; ++kk)
#pragma unroll
        for (int ni = 0; ni < 2; ++ni)
          bfr[kk][ni] = *(const bf16x8*)(bq + (size_t)(ks * 2 + kk) * 8192u + (size_t)ni * 512u);
#pragma unroll
      for (int mi = 0; mi < 2; ++mi)
#pragma unroll
        for (int kk = 0; kk < 2; ++kk)
          af[mi][kk] = *(const bf16x8*)(Ac + ((rA + (uint32_t)(mi * 32) * A_STRIDE_B
                                               + (uint32_t)(ks * 64 + kk * 32)) ^ fA));
#pragma unroll
      for (int mi = 0; mi < 2; ++mi)
#pragma unroll
        for (int ni = 0; ni < 2; ++ni)
#pragma unroll
          for (int kk = 0; kk < 2; ++kk)
            acc[mi][ni] = __builtin_amdgcn_mfma_f32_32x32x16_bf16(af[mi][kk], bfr[kk][ni],
                                                                  acc[mi][ni], 0, 0, 0);
    }

    __syncthreads();   // one barrier: A(s+1) writes visible; Ac safe to overwrite next step
    xv0 = xn0; xv1 = xn1;
  }

  // ---- epilogue: tanh -> bf16 h. C/D map (m74/m101): col=lane&31, row=(reg&3)+8*(reg>>2)+4*(lane>>5)
#pragma unroll
  for (int mi = 0; mi < 2; ++mi)
#pragma unroll
    for (int ni = 0; ni < 2; ++ni)
#pragma unroll
      for (int rg = 0; rg < 16; ++rg) {
        int rowi = (rg & 3) + 8 * (rg >> 2) + 4 * lhi2;
        int grow = row0 + wr * 64 + mi * 32 + rowi;
        int gcol = col0 + wc * 64 + ni * 32 + l32;
        hout[(size_t)grow * HID + gcol] = f2bf(fast_tanh(acc[mi][ni][rg]));
      }
}

// ---------------- kfinal (MFMA): 64 rows/block, all 64 output cols ----------------
__global__ __launch_bounds__(256) void kfinal(const unsigned short* __restrict__ h,
                                              const float* __restrict__ lw,
                                              const float* __restrict__ lb,
                                              float* __restrict__ out) {
  __shared__ unsigned short Ws[64 * 512];
  char* WsB = (char*)Ws;
  const int tid  = threadIdx.x;
  const int lane = tid & 63;
  const int wv   = tid >> 6;
  const int l16  = lane & 15;
  const int lhi  = lane >> 4;
  const int row0 = blockIdx.x * 64;

#pragma unroll
  for (int it = 0; it < 16; ++it) {
    int c = it * 256 + tid;
    int r = c >> 6;
    int k8 = (c & 63) * 8;
    const float* g = lw + r * 512 + k8;
    float4 f0 = *(const float4*)g;
    float4 f1 = *(const float4*)(g + 4);
    union { unsigned short s[8]; bf16x8 v; } u;
    u.s[0] = f2bf(f0.x); u.s[1] = f2bf(f0.y); u.s[2] = f2bf(f0.z); u.s[3] = f2bf(f0.w);
    u.s[4] = f2bf(f1.x); u.s[5] = f2bf(f1.y); u.s[6] = f2bf(f1.z); u.s[7] = f2bf(f1.w);
    *(bf16x8*)(WsB + swzw((uint32_t)r * 1024u + (uint32_t)k8 * 2u)) = u.v;
  }
  __syncthreads();

  const int arow = row0 + wv * 16 + l16;
  const unsigned short* ag = h + (size_t)arow * HID + lhi * 8;
  f32x4 acc[4] = {};
#pragma unroll
  for (int ks = 0; ks < 16; ++ks) {
    bf16x8 af = *(const bf16x8*)(ag + ks * 32);
#pragma unroll
    for (int ni = 0; ni < 4; ++ni) {
      uint32_t L = (uint32_t)(ni * 16 + l16) * 1024u + (uint32_t)(ks * 64 + lhi * 16);
      bf16x8 bfr = *(const bf16x8*)(WsB + swzw(L));
      acc[ni] = __builtin_amdgcn_mfma_f32_16x16x32_bf16(af, bfr, acc[ni], 0, 0, 0);
    }
  }
#pragma unroll
  for (int ni = 0; ni < 4; ++ni) {
    int col = ni * 16 + l16;
    float bias = lb[col];
#pragma unroll
    for (int rg = 0; rg < 4; ++rg) {
      int grow = row0 + wv * 16 + lhi * 4 + rg;
      out[(size_t)grow * 64 + col] = acc[ni][rg] + bias;
    }
  }
}

extern "C" void kernel_launch(void* const* d_in, const int* in_sizes, int n_in,
                              void* d_out, int out_size, void* d_ws, size_t ws_size,
                              hipStream_t stream) {
  const float* z  = (const float*)d_in[0];
  const float* ms = (const float*)d_in[1];
  const float* md = (const float*)d_in[2];
  const float* bw = (const float*)d_in[3];
  const float* sw = (const float*)d_in[4];
  const float* lw = (const float*)d_in[5];
  const float* lb = (const float*)d_in[6];
  float* out = (float*)d_out;

  unsigned short* Wf = (unsigned short*)d_ws;                        // 7.5 MiB fragment-linear W
  unsigned short* hb = (unsigned short*)((char*)d_ws + (8u << 20));  // 32 MiB bf16 h [32768][512]

  (void)hipFuncSetAttribute((const void*)kgemm1,
                            hipFuncAttributeMaxDynamicSharedMemorySize, LDS_BYTES);

  kpack<<<(HID * IN_DIM) / 256, 256, 0, stream>>>(bw, sw, Wf);
  kgemm1<<<512, 512, LDS_BYTES, stream>>>(z, ms, md, Wf, hb);
  kfinal<<<32768 / 64, 256, 0, stream>>>(hb, lw, lb, out);
}

// Round 20
// 279.326 us; speedup vs baseline: 1.1839x; 1.1839x over previous
//
#include <hip/hip_runtime.h>
#include <hip/hip_bf16.h>
#include <cstdint>

#define DI __device__ __forceinline__

using bf16x8 = __attribute__((ext_vector_type(8))) short;
using f32x4  = __attribute__((ext_vector_type(4))) float;

constexpr int IN_DIM = 384;
constexpr int HID    = 512;
constexpr int KTOT   = IN_DIM * 20;          // 7680: k = i*20 + t
constexpr int BM = 64, BN = 256, BK = 160;   // 8 input dims per K-step
constexpr int NSTEP = KTOT / BK;             // 48
// R18 structure at 4x occupancy: BM 128->64, 256 threads (4 waves, wave tile 64x64).
// A: double-buffered LDS, stride 320 + bijective XOR (addr^(row&7)<<4) write & read.
//    ONE barrier per step. 2x20480 = 40960 B/block -> 4 blocks/CU (16 waves, 4/SIMD)
//    to hide the ~200cy L2 latency of B-fragment loads (R18 ran 1 block/CU, 2 waves/SIMD).
// B: fragment-linear global (L2-resident 3.75MB slice/XCD), coalesced 1KB frag loads.
constexpr int A_STRIDE_B = 320;
constexpr int A_BYTES    = BM * A_STRIDE_B;        // 20480
constexpr int LDS_BYTES  = 2 * A_BYTES;            // 40960 -> 4 blocks/CU

DI unsigned short f2bf(float f) {
  union { float f; uint32_t u; } v; v.f = f;
  uint32_t r = (v.u + 0x7FFFu + ((v.u >> 16) & 1u)) >> 16;
  return (unsigned short)r;
}
DI float fast_tanh(float x) {
  float e = __expf(2.0f * x);
  return 1.0f - 2.0f / (e + 1.0f);
}
DI uint32_t swzw(uint32_t L) { return L ^ ((L >> 6) & 0x70u); }

// ---------------- kpack: W -> bf16 fragment-linear Wf (16x16x32 layout, R18-verbatim) ----
// Element (o,k): g = o>>4, q = k>>5; lane = (o&15) + ((k>>3)&3)*16;
// elem offset = (q*32 + g)*512 + lane*8 + (k&7).  k = i*20 + c; c==0 -> base else spline.
__global__ __launch_bounds__(256) void kpack(const float* __restrict__ bw,
                                             const float* __restrict__ sw,
                                             unsigned short* __restrict__ Wf) {
  int idx = blockIdx.x * 256 + threadIdx.x;   // o*384 + i
  int o = idx / IN_DIM;
  int i = idx - o * IN_DIM;
  const float* sp = sw + (size_t)idx * 19;
  const uint32_t gq  = (uint32_t)(o >> 4);
  const uint32_t l16o = (uint32_t)(o & 15);
#pragma unroll
  for (int c = 0; c < 20; ++c) {
    int k = i * 20 + c;
    uint32_t q  = (uint32_t)k >> 5;
    uint32_t kr = (uint32_t)k & 31u;
    uint32_t lane = l16o + ((kr >> 3) << 4);
    uint32_t off = (q * 32u + gq) * 512u + lane * 8u + (kr & 7u);
    float v = (c == 0) ? bw[idx] : sp[c - 1];
    Wf[off] = f2bf(v);
  }
}

// ---------------- fused KAN GEMM: h = tanh(A(x) @ W^T), 4 waves, wave tile 64x64 ----------------
__global__ __launch_bounds__(256, 4) void kgemm1(const float* __restrict__ z,
                                                 const float* __restrict__ ms,
                                                 const float* __restrict__ md,
                                                 const unsigned short* __restrict__ Wf,
                                                 unsigned short* __restrict__ hout) {
  extern __shared__ char ldsbuf[];            // [A0 @0][A1 @20480]

  const int tid  = threadIdx.x;
  const int lane = tid & 63;
  const int wv   = tid >> 6;                  // 0..3
  const int wc   = wv & 3;                    // N strip (64 cols); wave M strip = all 64 rows
  const int l16  = lane & 15;
  const int lhi  = lane >> 4;

  // XCD-aware bijective swizzle: grid 1024 = 8 XCD * 128; XCDs 0-3 -> nblk 0, 4-7 -> nblk 1
  int wg = blockIdx.x;
  int id = (wg & 7) * 128 + (wg >> 3);
  const int mblk = id & 511;
  const int nblk = id >> 9;
  const int row0 = mblk * BM;
  const int col0 = nblk * BN;

  // B global fragment base: g = nblk*16 + wc*4 + ni; q = s*5 + ks (frag stride 16384 elems)
  const unsigned short* bpt = Wf + (size_t)(nblk * 16 + wc * 4) * 512 + (size_t)lane * 8;

  // A-gen: isl constant per thread; 2 rows (arow0, arow0+32) per thread
  const int isl = tid & 7;
  const int arow0 = tid >> 3;                 // 0..31
  const uint32_t fw = ((uint32_t)arow0 & 7u) << 4;   // (row&7) invariant under +32

  // A fragment read base (XOR applied to full address; R18-verbatim)
  const uint32_t fA = (uint32_t)(l16 & 7) << 4;      // row&7 = l16&7
  const uint32_t rA = (uint32_t)l16 * A_STRIDE_B + (uint32_t)lhi * 16u;

  f32x4 acc[4][4] = {};

  // ---- prologue: stage A(0) into parity 0; prefetch x(1)
  float xv0, xv1;
  {
    const float* xcol = z + isl;              // s=0 -> i=isl<128 -> z
    float x0 = xcol[(size_t)(row0 + arow0) * 128];
    float x1 = xcol[(size_t)(row0 + arow0 + 32) * 128];
#pragma unroll
    for (int r = 0; r < 2; ++r) {
      float x = (r == 0) ? x0 : x1;
      int arow = arow0 + r * 32;
      float xt = fast_tanh(x);
      float tt = (xt + 1.0f) * 8.0f;
      int   m  = (int)tt; m = m > 16 ? 16 : m;
      float u  = tt - (float)m;
      float omu = 1.0f - u;
      float u2 = u * u, u3 = u2 * u;
      float w0 = omu * omu * omu * (1.0f / 6.0f);
      float w1 = (3.0f * u3 - 6.0f * u2 + 4.0f) * (1.0f / 6.0f);
      float w2 = (-3.0f * u3 + 3.0f * u2 + 3.0f * u + 1.0f) * (1.0f / 6.0f);
      float w3 = u3 * (1.0f / 6.0f);
      float sil = xt / (1.0f + __expf(-xt));
      uint32_t base = (uint32_t)arow * A_STRIDE_B + (uint32_t)isl * 40u;
#pragma unroll
      for (int zz = 0; zz < 5; ++zz)
        *(uint64_t*)(ldsbuf + ((base + zz * 8) ^ fw)) = 0ull;
      *(short*)(ldsbuf + (base ^ fw)) = (short)f2bf(sil);
      *(short*)(ldsbuf + ((base + 2u * (m + 1)) ^ fw)) = (short)f2bf(w0);
      *(short*)(ldsbuf + ((base + 2u * (m + 2)) ^ fw)) = (short)f2bf(w1);
      *(short*)(ldsbuf + ((base + 2u * (m + 3)) ^ fw)) = (short)f2bf(w2);
      if (m < 16)
        *(short*)(ldsbuf + ((base + 2u * (m + 4)) ^ fw)) = (short)f2bf(w3);
    }
    const float* xc1 = z + (8 + isl);         // i = 8+isl < 128 -> z
    xv0 = xc1[(size_t)(row0 + arow0) * 128];
    xv1 = xc1[(size_t)(row0 + arow0 + 32) * 128];
  }
  __syncthreads();

  for (int s = 0; s < NSTEP; ++s) {
    const uint32_t pc = (uint32_t)(s & 1);
    const uint32_t pn = pc ^ 1u;
    char* An = ldsbuf + pn * (uint32_t)A_BYTES;
    const char* Ac = ldsbuf + pc * (uint32_t)A_BYTES;

    float xn0 = 0.f, xn1 = 0.f;
    if (s + 1 < NSTEP) {
      // ---- stage A(s+1) into An using xv = x(s+1)
#pragma unroll
      for (int r = 0; r < 2; ++r) {
        float x = (r == 0) ? xv0 : xv1;
        int arow = arow0 + r * 32;
        float xt = fast_tanh(x);
        float tt = (xt + 1.0f) * 8.0f;
        int   m  = (int)tt; m = m > 16 ? 16 : m;
        float u  = tt - (float)m;
        float omu = 1.0f - u;
        float u2 = u * u, u3 = u2 * u;
        float w0 = omu * omu * omu * (1.0f / 6.0f);
        float w1 = (3.0f * u3 - 6.0f * u2 + 4.0f) * (1.0f / 6.0f);
        float w2 = (-3.0f * u3 + 3.0f * u2 + 3.0f * u + 1.0f) * (1.0f / 6.0f);
        float w3 = u3 * (1.0f / 6.0f);
        float sil = xt / (1.0f + __expf(-xt));
        uint32_t base = (uint32_t)arow * A_STRIDE_B + (uint32_t)isl * 40u;
#pragma unroll
        for (int zz = 0; zz < 5; ++zz)
          *(uint64_t*)(An + ((base + zz * 8) ^ fw)) = 0ull;
        *(short*)(An + (base ^ fw)) = (short)f2bf(sil);
        *(short*)(An + ((base + 2u * (m + 1)) ^ fw)) = (short)f2bf(w0);
        *(short*)(An + ((base + 2u * (m + 2)) ^ fw)) = (short)f2bf(w1);
        *(short*)(An + ((base + 2u * (m + 3)) ^ fw)) = (short)f2bf(w2);
        if (m < 16)
          *(short*)(An + ((base + 2u * (m + 4)) ^ fw)) = (short)f2bf(w3);
      }
      // ---- prefetch x(s+2)
      if (s + 2 < NSTEP) {
        int i = (s + 2) * 8 + isl;
        const float* src = (i < 128) ? z : (i < 256 ? ms : md);
        const float* xcol = src + (i & 127);
        xn0 = xcol[(size_t)(row0 + arow0) * 128];
        xn1 = xcol[(size_t)(row0 + arow0 + 32) * 128];
      }
    }

    // ---- compute(s): A frags from LDS (parity pc), B frags as coalesced 1KB global loads
    const size_t qoff = (size_t)s * 5u * 16384u;   // q = s*5 + ks
#pragma unroll
    for (int ks = 0; ks < 5; ++ks) {
      bf16x8 af[4], bfr[4];
#pragma unroll
      for (int ni = 0; ni < 4; ++ni)
        bfr[ni] = *(const bf16x8*)(bpt + qoff + (size_t)ks * 16384u + (size_t)ni * 512u);
#pragma unroll
      for (int mi = 0; mi < 4; ++mi)
        af[mi] = *(const bf16x8*)(Ac + ((rA + (uint32_t)(mi * 16) * A_STRIDE_B + ks * 64u) ^ fA));
#pragma unroll
      for (int mi = 0; mi < 4; ++mi)
#pragma unroll
        for (int ni = 0; ni < 4; ++ni)
          acc[mi][ni] = __builtin_amdgcn_mfma_f32_16x16x32_bf16(af[mi], bfr[ni], acc[mi][ni], 0, 0, 0);
    }

    __syncthreads();   // one barrier: A(s+1) writes visible; Ac safe to overwrite next step
    xv0 = xn0; xv1 = xn1;
  }

  // ---- epilogue: tanh -> bf16 h
#pragma unroll
  for (int mi = 0; mi < 4; ++mi)
#pragma unroll
    for (int ni = 0; ni < 4; ++ni)
#pragma unroll
      for (int rg = 0; rg < 4; ++rg) {
        int grow = row0 + mi * 16 + lhi * 4 + rg;
        int gcol = col0 + wc * 64 + ni * 16 + l16;
        hout[(size_t)grow * HID + gcol] = f2bf(fast_tanh(acc[mi][ni][rg]));
      }
}

// ---------------- kfinal (MFMA): 64 rows/block, all 64 output cols ----------------
__global__ __launch_bounds__(256) void kfinal(const unsigned short* __restrict__ h,
                                              const float* __restrict__ lw,
                                              const float* __restrict__ lb,
                                              float* __restrict__ out) {
  __shared__ unsigned short Ws[64 * 512];
  char* WsB = (char*)Ws;
  const int tid  = threadIdx.x;
  const int lane = tid & 63;
  const int wv   = tid >> 6;
  const int l16  = lane & 15;
  const int lhi  = lane >> 4;
  const int row0 = blockIdx.x * 64;

#pragma unroll
  for (int it = 0; it < 16; ++it) {
    int c = it * 256 + tid;
    int r = c >> 6;
    int k8 = (c & 63) * 8;
    const float* g = lw + r * 512 + k8;
    float4 f0 = *(const float4*)g;
    float4 f1 = *(const float4*)(g + 4);
    union { unsigned short s[8]; bf16x8 v; } u;
    u.s[0] = f2bf(f0.x); u.s[1] = f2bf(f0.y); u.s[2] = f2bf(f0.z); u.s[3] = f2bf(f0.w);
    u.s[4] = f2bf(f1.x); u.s[5] = f2bf(f1.y); u.s[6] = f2bf(f1.z); u.s[7] = f2bf(f1.w);
    *(bf16x8*)(WsB + swzw((uint32_t)r * 1024u + (uint32_t)k8 * 2u)) = u.v;
  }
  __syncthreads();

  const int arow = row0 + wv * 16 + l16;
  const unsigned short* ag = h + (size_t)arow * HID + lhi * 8;
  f32x4 acc[4] = {};
#pragma unroll
  for (int ks = 0; ks < 16; ++ks) {
    bf16x8 af = *(const bf16x8*)(ag + ks * 32);
#pragma unroll
    for (int ni = 0; ni < 4; ++ni) {
      uint32_t L = (uint32_t)(ni * 16 + l16) * 1024u + (uint32_t)(ks * 64 + lhi * 16);
      bf16x8 bfr = *(const bf16x8*)(WsB + swzw(L));
      acc[ni] = __builtin_amdgcn_mfma_f32_16x16x32_bf16(af, bfr, acc[ni], 0, 0, 0);
    }
  }
#pragma unroll
  for (int ni = 0; ni < 4; ++ni) {
    int col = ni * 16 + l16;
    float bias = lb[col];
#pragma unroll
    for (int rg = 0; rg < 4; ++rg) {
      int grow = row0 + wv * 16 + lhi * 4 + rg;
      out[(size_t)grow * 64 + col] = acc[ni][rg] + bias;
    }
  }
}

extern "C" void kernel_launch(void* const* d_in, const int* in_sizes, int n_in,
                              void* d_out, int out_size, void* d_ws, size_t ws_size,
                              hipStream_t stream) {
  const float* z  = (const float*)d_in[0];
  const float* ms = (const float*)d_in[1];
  const float* md = (const float*)d_in[2];
  const float* bw = (const float*)d_in[3];
  const float* sw = (const float*)d_in[4];
  const float* lw = (const float*)d_in[5];
  const float* lb = (const float*)d_in[6];
  float* out = (float*)d_out;

  unsigned short* Wf = (unsigned short*)d_ws;                        // 7.5 MiB fragment-linear W
  unsigned short* hb = (unsigned short*)((char*)d_ws + (8u << 20));  // 32 MiB bf16 h [32768][512]

  (void)hipFuncSetAttribute((const void*)kgemm1,
                            hipFuncAttributeMaxDynamicSharedMemorySize, LDS_BYTES);

  kpack<<<(HID * IN_DIM) / 256, 256, 0, stream>>>(bw, sw, Wf);
  kgemm1<<<1024, 256, LDS_BYTES, stream>>>(z, ms, md, Wf, hb);
  kfinal<<<32768 / 64, 256, 0, stream>>>(hb, lw, lb, out);
}

// Round 21
// 256.983 us; speedup vs baseline: 1.2868x; 1.0869x over previous
//
#include <hip/hip_runtime.h>
#include <hip/hip_bf16.h>
#include <cstdint>

#define DI __device__ __forceinline__

using bf16x8 = __attribute__((ext_vector_type(8))) short;
using f32x4  = __attribute__((ext_vector_type(4))) float;

constexpr int IN_DIM = 384;
constexpr int HID    = 512;
constexpr int KTOT   = IN_DIM * 20;          // 7680: k = i*20 + t
constexpr int BM = 64, BN = 512, BK = 160;   // 8 input dims per K-step; BN = full HID
constexpr int NSTEP = KTOT / BK;             // 48
// BN=512 kills the nblk redundancy (R20: FETCH showed 2x x-refetch, WRITE showed split-row
// amplification, VALU 42% from duplicated A-gen). 512 thr = 8 waves, wave tile 64x64.
// A: double-buffered LDS, stride 320 + bijective XOR (addr^(row&7)<<4) write & read.
//    ONE barrier per step. 2x20480 = 40960 B/block -> 2 blocks/CU, 16 waves/CU.
// B: fragment-linear global (L2-resident scan), coalesced 1KB frag loads. (R18/R20-verbatim)
constexpr int A_STRIDE_B = 320;
constexpr int A_BYTES    = BM * A_STRIDE_B;        // 20480
constexpr int LDS_BYTES  = 2 * A_BYTES;            // 40960

DI unsigned short f2bf(float f) {
  union { float f; uint32_t u; } v; v.f = f;
  uint32_t r = (v.u + 0x7FFFu + ((v.u >> 16) & 1u)) >> 16;
  return (unsigned short)r;
}
DI float fast_tanh(float x) {
  float e = __expf(2.0f * x);
  return 1.0f - 2.0f / (e + 1.0f);
}
DI uint32_t swzw(uint32_t L) { return L ^ ((L >> 6) & 0x70u); }

// ---------------- kpack: W -> bf16 fragment-linear Wf (16x16x32 layout, R18-verbatim) ----
__global__ __launch_bounds__(256) void kpack(const float* __restrict__ bw,
                                             const float* __restrict__ sw,
                                             unsigned short* __restrict__ Wf) {
  int idx = blockIdx.x * 256 + threadIdx.x;   // o*384 + i
  int o = idx / IN_DIM;
  int i = idx - o * IN_DIM;
  const float* sp = sw + (size_t)idx * 19;
  const uint32_t gq  = (uint32_t)(o >> 4);
  const uint32_t l16o = (uint32_t)(o & 15);
#pragma unroll
  for (int c = 0; c < 20; ++c) {
    int k = i * 20 + c;
    uint32_t q  = (uint32_t)k >> 5;
    uint32_t kr = (uint32_t)k & 31u;
    uint32_t lane = l16o + ((kr >> 3) << 4);
    uint32_t off = (q * 32u + gq) * 512u + lane * 8u + (kr & 7u);
    float v = (c == 0) ? bw[idx] : sp[c - 1];
    Wf[off] = f2bf(v);
  }
}

// ---------------- fused KAN GEMM: h = tanh(A(x) @ W^T), 8 waves, wave tile 64x64 ----------------
__global__ __launch_bounds__(512, 4) void kgemm1(const float* __restrict__ z,
                                                 const float* __restrict__ ms,
                                                 const float* __restrict__ md,
                                                 const unsigned short* __restrict__ Wf,
                                                 unsigned short* __restrict__ hout) {
  extern __shared__ char ldsbuf[];            // [A0 @0][A1 @20480]

  const int tid  = threadIdx.x;
  const int lane = tid & 63;
  const int wc   = tid >> 6;                  // 0..7 : N strip (64 cols); all waves share rows
  const int l16  = lane & 15;
  const int lhi  = lane >> 4;

  // XCD-aware bijective swizzle: grid 512 = 8 XCD * 64 (pure M split; every block scans W)
  int wg = blockIdx.x;
  int id = (wg & 7) * 64 + (wg >> 3);
  const int row0 = id * BM;

  // B global fragment base: g = wc*4 + ni in [0,32); q = s*5 + ks (frag stride 16384 elems)
  const unsigned short* bpt = Wf + (size_t)(wc * 4) * 512 + (size_t)lane * 8;

  // A-gen: exactly ONE task per thread (64 rows x 8 isl = 512)
  const int isl = tid & 7;
  const int arow = tid >> 3;                  // 0..63
  const uint32_t fw = ((uint32_t)arow & 7u) << 4;
  const uint32_t abase = (uint32_t)arow * A_STRIDE_B + (uint32_t)isl * 40u;

  // A fragment read base (XOR applied to full address; R18-verbatim)
  const uint32_t fA = (uint32_t)(l16 & 7) << 4;      // row&7 = l16&7
  const uint32_t rA = (uint32_t)l16 * A_STRIDE_B + (uint32_t)lhi * 16u;

  f32x4 acc[4][4] = {};

  // ---- prologue: stage A(0) into parity 0; prefetch x(1)
  float xv0;
  {
    float x = z[(size_t)(row0 + arow) * 128 + isl];   // s=0 -> i=isl<128 -> z
    float xt = fast_tanh(x);
    float tt = (xt + 1.0f) * 8.0f;
    int   m  = (int)tt; m = m > 16 ? 16 : m;
    float u  = tt - (float)m;
    float omu = 1.0f - u;
    float u2 = u * u, u3 = u2 * u;
    float w0 = omu * omu * omu * (1.0f / 6.0f);
    float w1 = (3.0f * u3 - 6.0f * u2 + 4.0f) * (1.0f / 6.0f);
    float w2 = (-3.0f * u3 + 3.0f * u2 + 3.0f * u + 1.0f) * (1.0f / 6.0f);
    float w3 = u3 * (1.0f / 6.0f);
    float sil = xt / (1.0f + __expf(-xt));
#pragma unroll
    for (int zz = 0; zz < 5; ++zz)
      *(uint64_t*)(ldsbuf + ((abase + zz * 8) ^ fw)) = 0ull;
    *(short*)(ldsbuf + (abase ^ fw)) = (short)f2bf(sil);
    *(short*)(ldsbuf + ((abase + 2u * (m + 1)) ^ fw)) = (short)f2bf(w0);
    *(short*)(ldsbuf + ((abase + 2u * (m + 2)) ^ fw)) = (short)f2bf(w1);
    *(short*)(ldsbuf + ((abase + 2u * (m + 3)) ^ fw)) = (short)f2bf(w2);
    if (m < 16)
      *(short*)(ldsbuf + ((abase + 2u * (m + 4)) ^ fw)) = (short)f2bf(w3);
    xv0 = z[(size_t)(row0 + arow) * 128 + 8 + isl];   // x(1)
  }
  __syncthreads();

  for (int s = 0; s < NSTEP; ++s) {
    const uint32_t pc = (uint32_t)(s & 1);
    const uint32_t pn = pc ^ 1u;
    char* An = ldsbuf + pn * (uint32_t)A_BYTES;
    const char* Ac = ldsbuf + pc * (uint32_t)A_BYTES;

    float xn0 = 0.f;
    if (s + 1 < NSTEP) {
      // ---- stage A(s+1) into An using xv0 = x(s+1)
      float xt = fast_tanh(xv0);
      float tt = (xt + 1.0f) * 8.0f;
      int   m  = (int)tt; m = m > 16 ? 16 : m;
      float u  = tt - (float)m;
      float omu = 1.0f - u;
      float u2 = u * u, u3 = u2 * u;
      float w0 = omu * omu * omu * (1.0f / 6.0f);
      float w1 = (3.0f * u3 - 6.0f * u2 + 4.0f) * (1.0f / 6.0f);
      float w2 = (-3.0f * u3 + 3.0f * u2 + 3.0f * u + 1.0f) * (1.0f / 6.0f);
      float w3 = u3 * (1.0f / 6.0f);
      float sil = xt / (1.0f + __expf(-xt));
#pragma unroll
      for (int zz = 0; zz < 5; ++zz)
        *(uint64_t*)(An + ((abase + zz * 8) ^ fw)) = 0ull;
      *(short*)(An + (abase ^ fw)) = (short)f2bf(sil);
      *(short*)(An + ((abase + 2u * (m + 1)) ^ fw)) = (short)f2bf(w0);
      *(short*)(An + ((abase + 2u * (m + 2)) ^ fw)) = (short)f2bf(w1);
      *(short*)(An + ((abase + 2u * (m + 3)) ^ fw)) = (short)f2bf(w2);
      if (m < 16)
        *(short*)(An + ((abase + 2u * (m + 4)) ^ fw)) = (short)f2bf(w3);
      // ---- prefetch x(s+2)
      if (s + 2 < NSTEP) {
        int i = (s + 2) * 8 + isl;
        const float* src = (i < 128) ? z : (i < 256 ? ms : md);
        xn0 = src[(size_t)(row0 + arow) * 128 + (i & 127)];
      }
    }

    // ---- compute(s): A frags from LDS (parity pc), B frags as coalesced 1KB global loads
    const size_t qoff = (size_t)s * 5u * 16384u;   // q = s*5 + ks
#pragma unroll
    for (int ks = 0; ks < 5; ++ks) {
      bf16x8 af[4], bfr[4];
#pragma unroll
      for (int ni = 0; ni < 4; ++ni)
        bfr[ni] = *(const bf16x8*)(bpt + qoff + (size_t)ks * 16384u + (size_t)ni * 512u);
#pragma unroll
      for (int mi = 0; mi < 4; ++mi)
        af[mi] = *(const bf16x8*)(Ac + ((rA + (uint32_t)(mi * 16) * A_STRIDE_B + ks * 64u) ^ fA));
#pragma unroll
      for (int mi = 0; mi < 4; ++mi)
#pragma unroll
        for (int ni = 0; ni < 4; ++ni)
          acc[mi][ni] = __builtin_amdgcn_mfma_f32_16x16x32_bf16(af[mi], bfr[ni], acc[mi][ni], 0, 0, 0);
    }

    __syncthreads();   // one barrier: A(s+1) writes visible; Ac safe to overwrite next step
    xv0 = xn0;
  }

  // ---- epilogue: tanh -> bf16 h (each row written entirely by one block)
#pragma unroll
  for (int mi = 0; mi < 4; ++mi)
#pragma unroll
    for (int ni = 0; ni < 4; ++ni)
#pragma unroll
      for (int rg = 0; rg < 4; ++rg) {
        int grow = row0 + mi * 16 + lhi * 4 + rg;
        int gcol = wc * 64 + ni * 16 + l16;
        hout[(size_t)grow * HID + gcol] = f2bf(fast_tanh(acc[mi][ni][rg]));
      }
}

// ---------------- kfinal (MFMA): 64 rows/block, all 64 output cols ----------------
__global__ __launch_bounds__(256) void kfinal(const unsigned short* __restrict__ h,
                                              const float* __restrict__ lw,
                                              const float* __restrict__ lb,
                                              float* __restrict__ out) {
  __shared__ unsigned short Ws[64 * 512];
  char* WsB = (char*)Ws;
  const int tid  = threadIdx.x;
  const int lane = tid & 63;
  const int wv   = tid >> 6;
  const int l16  = lane & 15;
  const int lhi  = lane >> 4;
  const int row0 = blockIdx.x * 64;

#pragma unroll
  for (int it = 0; it < 16; ++it) {
    int c = it * 256 + tid;
    int r = c >> 6;
    int k8 = (c & 63) * 8;
    const float* g = lw + r * 512 + k8;
    float4 f0 = *(const float4*)g;
    float4 f1 = *(const float4*)(g + 4);
    union { unsigned short s[8]; bf16x8 v; } u;
    u.s[0] = f2bf(f0.x); u.s[1] = f2bf(f0.y); u.s[2] = f2bf(f0.z); u.s[3] = f2bf(f0.w);
    u.s[4] = f2bf(f1.x); u.s[5] = f2bf(f1.y); u.s[6] = f2bf(f1.z); u.s[7] = f2bf(f1.w);
    *(bf16x8*)(WsB + swzw((uint32_t)r * 1024u + (uint32_t)k8 * 2u)) = u.v;
  }
  __syncthreads();

  const int arow = row0 + wv * 16 + l16;
  const unsigned short* ag = h + (size_t)arow * HID + lhi * 8;
  f32x4 acc[4] = {};
#pragma unroll
  for (int ks = 0; ks < 16; ++ks) {
    bf16x8 af = *(const bf16x8*)(ag + ks * 32);
#pragma unroll
    for (int ni = 0; ni < 4; ++ni) {
      uint32_t L = (uint32_t)(ni * 16 + l16) * 1024u + (uint32_t)(ks * 64 + lhi * 16);
      bf16x8 bfr = *(const bf16x8*)(WsB + swzw(L));
      acc[ni] = __builtin_amdgcn_mfma_f32_16x16x32_bf16(af, bfr, acc[ni], 0, 0, 0);
    }
  }
#pragma unroll
  for (int ni = 0; ni < 4; ++ni) {
    int col = ni * 16 + l16;
    float bias = lb[col];
#pragma unroll
    for (int rg = 0; rg < 4; ++rg) {
      int grow = row0 + wv * 16 + lhi * 4 + rg;
      out[(size_t)grow * 64 + col] = acc[ni][rg] + bias;
    }
  }
}

extern "C" void kernel_launch(void* const* d_in, const int* in_sizes, int n_in,
                              void* d_out, int out_size, void* d_ws, size_t ws_size,
                              hipStream_t stream) {
  const float* z  = (const float*)d_in[0];
  const float* ms = (const float*)d_in[1];
  const float* md = (const float*)d_in[2];
  const float* bw = (const float*)d_in[3];
  const float* sw = (const float*)d_in[4];
  const float* lw = (const float*)d_in[5];
  const float* lb = (const float*)d_in[6];
  float* out = (float*)d_out;

  unsigned short* Wf = (unsigned short*)d_ws;                        // 7.5 MiB fragment-linear W
  unsigned short* hb = (unsigned short*)((char*)d_ws + (8u << 20));  // 32 MiB bf16 h [32768][512]

  (void)hipFuncSetAttribute((const void*)kgemm1,
                            hipFuncAttributeMaxDynamicSharedMemorySize, LDS_BYTES);

  kpack<<<(HID * IN_DIM) / 256, 256, 0, stream>>>(bw, sw, Wf);
  kgemm1<<<512, 512, LDS_BYTES, stream>>>(z, ms, md, Wf, hb);
  kfinal<<<32768 / 64, 256, 0, stream>>>(hb, lw, lb, out);
}